// Round 3
// baseline (296.425 us; speedup 1.0000x reference)
//
#include <hip/hip_runtime.h>

#define NFFT    4096
#define NBINS   2049
#define TFRAMES 4096
#define HOP     1024
#define LFULL   4197376   // (TFRAMES-1)*HOP + NFFT
#define LOUT    4193280   // LFULL - NFFT  (== out_size/2 exactly)
#define CROP    2048      // NFFT/2

// base-4 digit reversal of a 12-bit index (involution)
__device__ __forceinline__ int drev12(int k) {
    unsigned r = __brev((unsigned)k) >> 20;          // 12-bit bit reversal
    r = ((r & 0x555u) << 1) | ((r >> 1) & 0x555u);   // swap bits within pairs
    return (int)r;
}

// LDS bank swizzle: keeps contiguous runs conflict-free, cuts early-stage
// stride-4/16 patterns from 8-way to <=4-way conflicts.
__device__ __forceinline__ int SW(int p) {
    return p ^ ((p >> 5) & 31);
}

__global__ __launch_bounds__(256) void fft_frames(
    const float* __restrict__ zr,      // z[0]: [NBINS][TFRAMES]
    const float* __restrict__ zi,      // z[1]: [NBINS][TFRAMES]
    const float* __restrict__ window,  // [NFFT]
    float* __restrict__ out)           // [2][LOUT], pre-zeroed; cropped accumulator
{
    __shared__ float sre[NFFT];
    __shared__ float sim[NFFT];
    const int t   = blockIdx.x;
    const int tid = threadIdx.x;

    // Load Hermitian-extended spectrum, digit-reversed, into LDS.
    // Iterate by DESTINATION p so LDS stores are contiguous (conflict-free);
    // global reads are scalar gathers (stride 16KB along f) but the 67MB
    // input is fully L3-resident.
    #pragma unroll
    for (int i = 0; i < NFFT / 256; ++i) {
        int p = tid + i * 256;
        int k = drev12(p);
        int f    = (k <= NFFT / 2) ? k : (NFFT - k);
        float sg = (k <= NFFT / 2) ? 1.0f : -1.0f;   // conj for upper half
        float a = zr[f * TFRAMES + t];
        float b = zi[f * TFRAMES + t] * sg;
        int q = SW(p);
        sre[q] = a;
        sim[q] = b;
    }
    __syncthreads();

    // 6 radix-4 DIT stages, inverse twiddles e^{+i...}, in-place
    // (each butterfly owns a disjoint quad -> no intra-stage hazard).
    #pragma unroll
    for (int s = 0; s < 6; ++s) {
        const int q = 1 << (2 * s);
        #pragma unroll
        for (int bb = 0; bb < 4; ++bb) {
            const int b  = tid + bb * 256;
            const int j  = b & (q - 1);
            const int i0 = ((b >> (2 * s)) << (2 * s + 2)) + j;
            const int p0 = SW(i0);
            const int p1 = SW(i0 + q);
            const int p2 = SW(i0 + 2 * q);
            const int p3 = SW(i0 + 3 * q);
            float x0r = sre[p0], x0i = sim[p0];
            float x1r = sre[p1], x1i = sim[p1];
            float x2r = sre[p2], x2i = sim[p2];
            float x3r = sre[p3], x3i = sim[p3];

            float ang = (float)j * (6.283185307179586f / (float)(4 * q));
            float s1, c1;
            __sincosf(ang, &s1, &c1);
            float c2 = c1 * c1 - s1 * s1, s2 = 2.0f * c1 * s1;    // w^2
            float c3 = c2 * c1 - s2 * s1, s3 = c2 * s1 + s2 * c1; // w^3

            float t1r = x1r * c1 - x1i * s1, t1i = x1r * s1 + x1i * c1;
            float t2r = x2r * c2 - x2i * s2, t2i = x2r * s2 + x2i * c2;
            float t3r = x3r * c3 - x3i * s3, t3i = x3r * s3 + x3i * c3;

            float a0r = x0r + t2r, a0i = x0i + t2i;
            float a1r = x0r - t2r, a1i = x0i - t2i;
            float a2r = t1r + t3r, a2i = t1i + t3i;
            float a3r = t1r - t3r, a3i = t1i - t3i;

            sre[p0] = a0r + a2r;  sim[p0] = a0i + a2i;   // y0 = a0 + a2
            sre[p1] = a1r - a3i;  sim[p1] = a1i + a3r;   // y1 = a1 + i*a3
            sre[p2] = a0r - a2r;  sim[p2] = a0i - a2i;   // y2 = a0 - a2
            sre[p3] = a1r + a3i;  sim[p3] = a1i - a3r;   // y3 = a1 - i*a3
        }
        __syncthreads();
    }

    // Window (fold 1/N), overlap-add via device-scope fp32 atomics directly
    // into the CROPPED output buffer; positions outside the crop are dropped.
    const int base = (t << 10) - CROP;   // t*HOP - NFFT/2
    #pragma unroll
    for (int i = 0; i < NFFT / 256; ++i) {
        int n = tid + i * 256;
        float w = window[n] * (1.0f / (float)NFFT);
        int p = SW(n);
        int P = base + n;
        if (P >= 0 && P < LOUT) {
            atomicAdd(&out[P],        sre[p] * w);
            atomicAdd(&out[LOUT + P], sim[p] * w);
        }
    }
}

__global__ __launch_bounds__(256) void normalize_inplace(
    const float* __restrict__ window,
    float* __restrict__ out)
{
    int p = blockIdx.x * 256 + threadIdx.x;
    if (p >= LOUT) return;
    int P = p + CROP;                            // position in uncropped signal
    // frames t with 0 <= P - HOP*t < NFFT
    int t_hi = min(TFRAMES - 1, P >> 10);
    int t_lo = max(0, (P - (NFFT - HOP)) >> 10);
    float ws = 0.0f;
    for (int tt = t_lo; tt <= t_hi; ++tt) ws += window[P - (tt << 10)];
    float inv = (ws >= 1e-6f) ? (1.0f / ws) : 1.0f;
    out[p]        *= inv;
    out[LOUT + p] *= inv;
}

extern "C" void kernel_launch(void* const* d_in, const int* in_sizes, int n_in,
                              void* d_out, int out_size, void* d_ws, size_t ws_size,
                              hipStream_t stream) {
    const float* z      = (const float*)d_in[0];
    const float* window = (const float*)d_in[1];
    const float* zr = z;
    const float* zi = z + (size_t)NBINS * TFRAMES;
    float* out = (float*)d_out;   // 2*LOUT floats; used as the OLA accumulator

    hipMemsetAsync(out, 0, (size_t)2 * LOUT * sizeof(float), stream);
    fft_frames<<<TFRAMES, 256, 0, stream>>>(zr, zi, window, out);
    normalize_inplace<<<(LOUT + 255) / 256, 256, 0, stream>>>(window, out);
}

// Round 4
// 253.842 us; speedup vs baseline: 1.1678x; 1.1678x over previous
//
#include <hip/hip_runtime.h>

#define NFFT    4096
#define NBINS   2049
#define TFRAMES 4096
#define HOP     1024
#define LFULL   4197376   // (TFRAMES-1)*HOP + NFFT
#define LOUT    4193280   // LFULL - NFFT  (== out_size/2 exactly)
#define CROP    2048      // NFFT/2
#define RS      2064      // transposed row stride in floats (64B-aligned rows)

// base-4 digit reversal of a 12-bit index (involution)
__device__ __forceinline__ int drev12(int k) {
    unsigned r = __brev((unsigned)k) >> 20;          // 12-bit bit reversal
    r = ((r & 0x555u) << 1) | ((r >> 1) & 0x555u);   // swap bits within pairs
    return (int)r;
}

// LDS bank swizzle; spreads digit-reversed scatter onto all 32 banks (2-way max).
__device__ __forceinline__ int SW(int p) {
    return p ^ ((p >> 5) & 31);
}

// ---------------- transpose: z[ch][f][t] -> zt[ch][t][f] (stride RS) ----------------
__global__ __launch_bounds__(256) void transpose_zt(
    const float* __restrict__ z,   // [2][NBINS][TFRAMES]
    float* __restrict__ zt)        // [2][TFRAMES][RS]
{
    __shared__ float tile[32][33];
    const int ch = blockIdx.z;
    const int f0 = blockIdx.x * 32;
    const int t0 = blockIdx.y * 32;
    const int tx = threadIdx.x;        // 0..31
    const int ty = threadIdx.y;        // 0..7
    const float* src = z + (size_t)ch * NBINS * TFRAMES;
    float* dst = zt + (size_t)ch * TFRAMES * RS;

    #pragma unroll
    for (int k = 0; k < 4; ++k) {
        int f = f0 + ty + 8 * k;
        if (f < NBINS)
            tile[ty + 8 * k][tx] = src[(size_t)f * TFRAMES + (t0 + tx)];
    }
    __syncthreads();
    #pragma unroll
    for (int k = 0; k < 4; ++k) {
        int f = f0 + tx;
        if (f < NBINS)
            dst[(size_t)(t0 + ty + 8 * k) * RS + f] = tile[tx][ty + 8 * k];
    }
}

// ---------------- FFT + windowed OLA, coalesced loads from zt ----------------
__global__ __launch_bounds__(256) void fft_frames_t(
    const float* __restrict__ zt,      // [2][TFRAMES][RS]
    const float* __restrict__ window,  // [NFFT]
    float* __restrict__ out)           // [2][LOUT], pre-zeroed; cropped accumulator
{
    __shared__ float sre[NFFT];
    __shared__ float sim[NFFT];
    const int t   = blockIdx.x;
    const int tid = threadIdx.x;
    const float* rowr = zt + (size_t)t * RS;
    const float* rowi = zt + (size_t)TFRAMES * RS + (size_t)t * RS;

    // Coalesced float4 loads of the half spectrum; dual scatter (value +
    // conjugate) into digit-reversed, swizzled LDS positions.
    const float4 ar0 = ((const float4*)rowr)[tid * 2];
    const float4 ar1 = ((const float4*)rowr)[tid * 2 + 1];
    const float4 ai0 = ((const float4*)rowi)[tid * 2];
    const float4 ai1 = ((const float4*)rowi)[tid * 2 + 1];
    float ra[8] = {ar0.x, ar0.y, ar0.z, ar0.w, ar1.x, ar1.y, ar1.z, ar1.w};
    float ia[8] = {ai0.x, ai0.y, ai0.z, ai0.w, ai1.x, ai1.y, ai1.z, ai1.w};
    #pragma unroll
    for (int u = 0; u < 8; ++u) {
        int f = 8 * tid + u;               // 0..2047
        int p1 = SW(drev12(f));
        sre[p1] = ra[u];
        sim[p1] = ia[u];
        if (f > 0) {                       // conj partner at bin 4096-f
            int p2 = SW(drev12(NFFT - f));
            sre[p2] = ra[u];
            sim[p2] = -ia[u];
        }
    }
    if (tid == 0) {                        // Nyquist bin (kept as-is, no conj)
        int p = SW(drev12(2048));
        sre[p] = rowr[2048];
        sim[p] = rowi[2048];
    }
    __syncthreads();

    // 6 radix-4 DIT stages, inverse twiddles, in-place (disjoint quads).
    #pragma unroll
    for (int s = 0; s < 6; ++s) {
        const int q = 1 << (2 * s);
        #pragma unroll
        for (int bb = 0; bb < 4; ++bb) {
            const int b  = tid + bb * 256;
            const int j  = b & (q - 1);
            const int i0 = ((b >> (2 * s)) << (2 * s + 2)) + j;
            const int p0 = SW(i0);
            const int p1 = SW(i0 + q);
            const int p2 = SW(i0 + 2 * q);
            const int p3 = SW(i0 + 3 * q);
            float x0r = sre[p0], x0i = sim[p0];
            float x1r = sre[p1], x1i = sim[p1];
            float x2r = sre[p2], x2i = sim[p2];
            float x3r = sre[p3], x3i = sim[p3];

            float ang = (float)j * (6.283185307179586f / (float)(4 * q));
            float s1, c1;
            __sincosf(ang, &s1, &c1);
            float c2 = c1 * c1 - s1 * s1, s2 = 2.0f * c1 * s1;    // w^2
            float c3 = c2 * c1 - s2 * s1, s3 = c2 * s1 + s2 * c1; // w^3

            float t1r = x1r * c1 - x1i * s1, t1i = x1r * s1 + x1i * c1;
            float t2r = x2r * c2 - x2i * s2, t2i = x2r * s2 + x2i * c2;
            float t3r = x3r * c3 - x3i * s3, t3i = x3r * s3 + x3i * c3;

            float a0r = x0r + t2r, a0i = x0i + t2i;
            float a1r = x0r - t2r, a1i = x0i - t2i;
            float a2r = t1r + t3r, a2i = t1i + t3i;
            float a3r = t1r - t3r, a3i = t1i - t3i;

            sre[p0] = a0r + a2r;  sim[p0] = a0i + a2i;   // y0 = a0 + a2
            sre[p1] = a1r - a3i;  sim[p1] = a1i + a3r;   // y1 = a1 + i*a3
            sre[p2] = a0r - a2r;  sim[p2] = a0i - a2i;   // y2 = a0 - a2
            sre[p3] = a1r + a3i;  sim[p3] = a1i - a3r;   // y3 = a1 - i*a3
        }
        __syncthreads();
    }

    // Window (fold 1/N), OLA via fp32 atomics into the CROPPED output.
    const int base = (t << 10) - CROP;
    #pragma unroll
    for (int i = 0; i < NFFT / 256; ++i) {
        int n = tid + i * 256;
        float w = window[n] * (1.0f / (float)NFFT);
        int p = SW(n);
        int P = base + n;
        if (P >= 0 && P < LOUT) {
            atomicAdd(&out[P],        sre[p] * w);
            atomicAdd(&out[LOUT + P], sim[p] * w);
        }
    }
}

// ---------------- fallback FFT (R3 gather version, used if ws too small) ----------------
__global__ __launch_bounds__(256) void fft_frames_gather(
    const float* __restrict__ zr, const float* __restrict__ zi,
    const float* __restrict__ window, float* __restrict__ out)
{
    __shared__ float sre[NFFT];
    __shared__ float sim[NFFT];
    const int t   = blockIdx.x;
    const int tid = threadIdx.x;
    #pragma unroll
    for (int i = 0; i < NFFT / 256; ++i) {
        int p = tid + i * 256;
        int k = drev12(p);
        int f    = (k <= NFFT / 2) ? k : (NFFT - k);
        float sg = (k <= NFFT / 2) ? 1.0f : -1.0f;
        float a = zr[f * TFRAMES + t];
        float b = zi[f * TFRAMES + t] * sg;
        int q = SW(p);
        sre[q] = a;
        sim[q] = b;
    }
    __syncthreads();
    #pragma unroll
    for (int s = 0; s < 6; ++s) {
        const int q = 1 << (2 * s);
        #pragma unroll
        for (int bb = 0; bb < 4; ++bb) {
            const int b  = tid + bb * 256;
            const int j  = b & (q - 1);
            const int i0 = ((b >> (2 * s)) << (2 * s + 2)) + j;
            const int p0 = SW(i0), p1 = SW(i0 + q), p2 = SW(i0 + 2 * q), p3 = SW(i0 + 3 * q);
            float x0r = sre[p0], x0i = sim[p0];
            float x1r = sre[p1], x1i = sim[p1];
            float x2r = sre[p2], x2i = sim[p2];
            float x3r = sre[p3], x3i = sim[p3];
            float ang = (float)j * (6.283185307179586f / (float)(4 * q));
            float s1, c1; __sincosf(ang, &s1, &c1);
            float c2 = c1 * c1 - s1 * s1, s2 = 2.0f * c1 * s1;
            float c3 = c2 * c1 - s2 * s1, s3 = c2 * s1 + s2 * c1;
            float t1r = x1r * c1 - x1i * s1, t1i = x1r * s1 + x1i * c1;
            float t2r = x2r * c2 - x2i * s2, t2i = x2r * s2 + x2i * c2;
            float t3r = x3r * c3 - x3i * s3, t3i = x3r * s3 + x3i * c3;
            float a0r = x0r + t2r, a0i = x0i + t2i;
            float a1r = x0r - t2r, a1i = x0i - t2i;
            float a2r = t1r + t3r, a2i = t1i + t3i;
            float a3r = t1r - t3r, a3i = t1i - t3i;
            sre[p0] = a0r + a2r;  sim[p0] = a0i + a2i;
            sre[p1] = a1r - a3i;  sim[p1] = a1i + a3r;
            sre[p2] = a0r - a2r;  sim[p2] = a0i - a2i;
            sre[p3] = a1r + a3i;  sim[p3] = a1i - a3r;
        }
        __syncthreads();
    }
    const int base = (t << 10) - CROP;
    #pragma unroll
    for (int i = 0; i < NFFT / 256; ++i) {
        int n = tid + i * 256;
        float w = window[n] * (1.0f / (float)NFFT);
        int p = SW(n);
        int P = base + n;
        if (P >= 0 && P < LOUT) {
            atomicAdd(&out[P],        sre[p] * w);
            atomicAdd(&out[LOUT + P], sim[p] * w);
        }
    }
}

// ---------------- normalize: interior wsum == 3/4096 exactly ----------------
__global__ __launch_bounds__(256) void normalize_inplace(
    const float* __restrict__ window,
    float* __restrict__ out)
{
    int idx = blockIdx.x * 256 + threadIdx.x;       // float4 index
    int p = idx * 4;
    if (p >= LOUT) return;
    if (p >= 1024 && p < LOUT - 1024) {
        // interior: 4 Hann taps at pi/2 phase steps sum to exactly 2
        const float inv = (float)NFFT / 3.0f;       // 1 / (2 * 1.5/NFFT)
        float4* o0 = (float4*)(out + p);
        float4* o1 = (float4*)(out + LOUT + p);
        float4 a = *o0, b = *o1;
        a.x *= inv; a.y *= inv; a.z *= inv; a.w *= inv;
        b.x *= inv; b.y *= inv; b.z *= inv; b.w *= inv;
        *o0 = a; *o1 = b;
    } else {
        for (int e = 0; e < 4; ++e) {
            int pe = p + e;
            int P = pe + CROP;
            int t_hi = min(TFRAMES - 1, P >> 10);
            int t_lo = max(0, (P - (NFFT - HOP)) >> 10);
            float ws = 0.0f;
            for (int tt = t_lo; tt <= t_hi; ++tt) ws += window[P - (tt << 10)];
            float inv = (ws >= 1e-6f) ? (1.0f / ws) : 1.0f;
            out[pe]        *= inv;
            out[LOUT + pe] *= inv;
        }
    }
}

extern "C" void kernel_launch(void* const* d_in, const int* in_sizes, int n_in,
                              void* d_out, int out_size, void* d_ws, size_t ws_size,
                              hipStream_t stream) {
    const float* z      = (const float*)d_in[0];
    const float* window = (const float*)d_in[1];
    float* out = (float*)d_out;   // 2*LOUT floats; doubles as the OLA accumulator

    hipMemsetAsync(out, 0, (size_t)2 * LOUT * sizeof(float), stream);

    const size_t ws_needed = (size_t)2 * TFRAMES * RS * sizeof(float);  // 67.6 MB
    if (ws_size >= ws_needed) {
        float* zt = (float*)d_ws;
        dim3 tg((NBINS + 31) / 32, TFRAMES / 32, 2);
        transpose_zt<<<tg, dim3(32, 8), 0, stream>>>(z, zt);
        fft_frames_t<<<TFRAMES, 256, 0, stream>>>(zt, window, out);
    } else {
        const float* zr = z;
        const float* zi = z + (size_t)NBINS * TFRAMES;
        fft_frames_gather<<<TFRAMES, 256, 0, stream>>>(zr, zi, window, out);
    }
    normalize_inplace<<<(LOUT / 4 + 255) / 256, 256, 0, stream>>>(window, out);
}

// Round 5
// 246.766 us; speedup vs baseline: 1.2012x; 1.0287x over previous
//
#include <hip/hip_runtime.h>

#define NFFT    4096
#define NBINS   2049
#define TFRAMES 4096
#define HOP     1024
#define LFULL   4197376   // (TFRAMES-1)*HOP + NFFT
#define LOUT    4193280   // LFULL - NFFT  (== out_size/2 exactly)
#define CROP    2048      // NFFT/2
#define RS      2064      // transposed row stride in floats (16B-aligned rows)

// ---- per-phase LDS swizzles (derived so all 4 access patterns are 2-way max) ----
__device__ __forceinline__ int SW1(int p) {
    return p ^ (((p >> 6) & 3) | (((p >> 9) & 3) << 2) | (((p >> 8) & 1) << 4));
}
__device__ __forceinline__ int SW2(int p) {
    return p ^ (((p >> 8) & 3) << 3);
}

// radix-4 DIT butterfly, no twiddle (j=0)
__device__ __forceinline__ void b4(float& x0r, float& x0i, float& x1r, float& x1i,
                                   float& x2r, float& x2i, float& x3r, float& x3i) {
    float a0r = x0r + x2r, a0i = x0i + x2i;
    float a1r = x0r - x2r, a1i = x0i - x2i;
    float a2r = x1r + x3r, a2i = x1i + x3i;
    float a3r = x1r - x3r, a3i = x1i - x3i;
    x0r = a0r + a2r;  x0i = a0i + a2i;
    x1r = a1r - a3i;  x1i = a1i + a3r;   // y1 = a1 + i*a3  (inverse FFT)
    x2r = a0r - a2r;  x2i = a0i - a2i;
    x3r = a1r + a3i;  x3i = a1i - a3r;   // y3 = a1 - i*a3
}

// radix-4 DIT butterfly with twiddle w = e^{+i*ang} given as (c1,s1)
__device__ __forceinline__ void b4t(float& x0r, float& x0i, float& x1r, float& x1i,
                                    float& x2r, float& x2i, float& x3r, float& x3i,
                                    float c1, float s1) {
    float c2 = c1 * c1 - s1 * s1, s2 = 2.0f * c1 * s1;    // w^2
    float c3 = c2 * c1 - s2 * s1, s3 = c2 * s1 + s2 * c1; // w^3
    float t1r = x1r * c1 - x1i * s1, t1i = x1r * s1 + x1i * c1;
    float t2r = x2r * c2 - x2i * s2, t2i = x2r * s2 + x2i * c2;
    float t3r = x3r * c3 - x3i * s3, t3i = x3r * s3 + x3i * c3;
    float a0r = x0r + t2r, a0i = x0i + t2i;
    float a1r = x0r - t2r, a1i = x0i - t2i;
    float a2r = t1r + t3r, a2i = t1i + t3i;
    float a3r = t1r - t3r, a3i = t1i - t3i;
    x0r = a0r + a2r;  x0i = a0i + a2i;
    x1r = a1r - a3i;  x1i = a1i + a3r;
    x2r = a0r - a2r;  x2i = a0i - a2i;
    x3r = a1r + a3i;  x3i = a1i - a3r;
}

// ---------------- transpose: z[ch][f][t] -> zt[ch][t][f], 64x64 float4 tiles ----------------
__global__ __launch_bounds__(256) void transpose64(
    const float* __restrict__ z,   // [2][NBINS][TFRAMES]
    float* __restrict__ zt)        // [2][TFRAMES][RS]
{
    __shared__ float tile[64][65];
    const int ch = blockIdx.z;
    const int f0 = blockIdx.x * 64;     // covers f in [0,2048)
    const int t0 = blockIdx.y * 64;
    const int tx = threadIdx.x & 15;    // float4 index along the minor dim
    const int ty = threadIdx.x >> 4;    // 0..15
    const float* src = z + (size_t)ch * NBINS * TFRAMES;
    float* dst = zt + (size_t)ch * TFRAMES * RS;

    #pragma unroll
    for (int k = 0; k < 4; ++k) {
        int fl = ty + 16 * k;
        float4 v = *(const float4*)(src + (size_t)(f0 + fl) * TFRAMES + t0 + 4 * tx);
        tile[fl][4 * tx + 0] = v.x;
        tile[fl][4 * tx + 1] = v.y;
        tile[fl][4 * tx + 2] = v.z;
        tile[fl][4 * tx + 3] = v.w;
    }
    __syncthreads();
    #pragma unroll
    for (int k = 0; k < 4; ++k) {
        int tl = ty + 16 * k;
        float4 v = make_float4(tile[4 * tx + 0][tl], tile[4 * tx + 1][tl],
                               tile[4 * tx + 2][tl], tile[4 * tx + 3][tl]);
        *(float4*)(dst + (size_t)(t0 + tl) * RS + f0 + 4 * tx) = v;
    }
}

// copy the single f=2048 row (NBINS = 2049 = 32*64 + 1)
__global__ __launch_bounds__(256) void edge2048(
    const float* __restrict__ z, float* __restrict__ zt)
{
    int i = blockIdx.x * 256 + threadIdx.x;      // 0 .. 8191
    int ch = i >> 12, t = i & 4095;
    zt[(size_t)ch * TFRAMES * RS + (size_t)t * RS + 2048] =
        z[(size_t)ch * NBINS * TFRAMES + (size_t)2048 * TFRAMES + t];
}

// ---------------- register radix-16^3 IFFT + windowed OLA ----------------
__global__ __launch_bounds__(256) void fft_reg(
    const float* __restrict__ zt,      // [2][TFRAMES][RS]
    float* __restrict__ out)           // [2][LOUT], pre-zeroed; cropped accumulator
{
    __shared__ float LRe[NFFT];
    __shared__ float LIm[NFFT];
    const int t = blockIdx.x;
    const int T = threadIdx.x;
    const float* rowr = zt + (size_t)t * RS;
    const float* rowi = zt + (size_t)TFRAMES * RS + (size_t)t * RS;

    // W16 twiddle table: cos/sin(k*pi/8), compile-time folded after unroll
    const float C16[16] = { 1.0f,  0.923879532511287f,  0.707106781186548f,  0.382683432365090f,
                            0.0f, -0.382683432365090f, -0.707106781186548f, -0.923879532511287f,
                           -1.0f, -0.923879532511287f, -0.707106781186548f, -0.382683432365090f,
                            0.0f,  0.382683432365090f,  0.707106781186548f,  0.923879532511287f };
    const float S16[16] = { 0.0f,  0.382683432365090f,  0.707106781186548f,  0.923879532511287f,
                            1.0f,  0.923879532511287f,  0.707106781186548f,  0.382683432365090f,
                            0.0f, -0.382683432365090f, -0.707106781186548f, -0.923879532511287f,
                           -1.0f, -0.923879532511287f, -0.707106781186548f, -0.382683432365090f };

    float xr[16], xi[16];

    // ---- Phase A: thread T owns digit-domain group G = drev8(T), i.e. natural
    // indices n = 256*m + T (coalesced!). Hermitian mirror for n > 2048.
    #pragma unroll
    for (int m = 0; m < 16; ++m) {
        int r = ((m & 3) << 2) | (m >> 2);        // drev4 (involution)
        int n = (m << 8) + T;
        if (n <= 2048) { xr[r] = rowr[n]; xi[r] = rowi[n]; }
        else { int f = NFFT - n; xr[r] = rowr[f]; xi[r] = -rowi[f]; }
    }
    // stage 0 (q=1, no twiddle): quads
    #pragma unroll
    for (int a = 0; a < 4; ++a)
        b4(xr[4*a], xi[4*a], xr[4*a+1], xi[4*a+1], xr[4*a+2], xi[4*a+2], xr[4*a+3], xi[4*a+3]);
    // stage 1 (q=4): ang = r0 * 2pi/16 -> table
    b4(xr[0], xi[0], xr[4], xi[4], xr[8], xi[8], xr[12], xi[12]);
    #pragma unroll
    for (int r0 = 1; r0 < 4; ++r0)
        b4t(xr[r0], xi[r0], xr[r0+4], xi[r0+4], xr[r0+8], xi[r0+8], xr[r0+12], xi[r0+12],
            C16[r0], S16[r0]);
    // write layout sigma1 at p = 16*drev8(T) + r
    {
        int G = ((T & 3) << 6) | (((T >> 2) & 3) << 4) | (((T >> 4) & 3) << 2) | ((T >> 6) & 3);
        int p0 = G << 4;
        #pragma unroll
        for (int r = 0; r < 16; ++r) {
            int a = SW1(p0 + r);
            LRe[a] = xr[r];  LIm[a] = xi[r];
        }
    }
    __syncthreads();

    // ---- Phase B: thread (H = T>>4, j = T&15) owns p = 256H + 16s + j
    const int H = T >> 4, j = T & 15;
    #pragma unroll
    for (int s = 0; s < 16; ++s) {
        int a = SW1((H << 8) + (s << 4) + j);
        xr[s] = LRe[a];  xi[s] = LIm[a];
    }
    // twiddles: base3 = j*2pi/256; stage-2 angle j*2pi/64 = 4*base3 (two doublings)
    float cb, sb;
    __sincosf((float)j * (6.283185307179586f / 256.0f), &sb, &cb);
    float cd = cb * cb - sb * sb, sd = 2.0f * cb * sb;      // j*2pi/128
    float c2s = cd * cd - sd * sd, s2s = 2.0f * cd * sd;    // j*2pi/64
    // stage 2 (q=16): same twiddle for all 4 quads
    if (j == 0) {
        #pragma unroll
        for (int a = 0; a < 4; ++a)
            b4(xr[4*a], xi[4*a], xr[4*a+1], xi[4*a+1], xr[4*a+2], xi[4*a+2], xr[4*a+3], xi[4*a+3]);
    } else {
        #pragma unroll
        for (int a = 0; a < 4; ++a)
            b4t(xr[4*a], xi[4*a], xr[4*a+1], xi[4*a+1], xr[4*a+2], xi[4*a+2], xr[4*a+3], xi[4*a+3],
                c2s, s2s);
    }
    // stage 3 (q=64): ang = (16*s0 + j)*2pi/256 = base3 + s0*pi/8
    #pragma unroll
    for (int s0 = 0; s0 < 4; ++s0) {
        float c = cb * C16[s0] - sb * S16[s0];
        float s = sb * C16[s0] + cb * S16[s0];
        if (s0 == 0 && j == 0)
            b4(xr[0], xi[0], xr[4], xi[4], xr[8], xi[8], xr[12], xi[12]);
        else
            b4t(xr[s0], xi[s0], xr[s0+4], xi[s0+4], xr[s0+8], xi[s0+8], xr[s0+12], xi[s0+12], c, s);
    }
    __syncthreads();   // all phase-B reads done before overwriting
    #pragma unroll
    for (int s = 0; s < 16; ++s) {
        int a = SW2((H << 8) + (s << 4) + j);
        LRe[a] = xr[s];  LIm[a] = xi[s];
    }
    __syncthreads();

    // ---- Phase C: thread d = T owns p = 256m + d (natural output n = p)
    #pragma unroll
    for (int m = 0; m < 16; ++m) {
        int a = SW2((m << 8) + T);
        xr[m] = LRe[a];  xi[m] = LIm[a];
    }
    // twiddles: base5 = d*2pi/4096; stage-4 angle d*2pi/1024 = 4*base5
    float c5, s5;
    __sincosf((float)T * (6.283185307179586f / 4096.0f), &s5, &c5);
    float cq = c5 * c5 - s5 * s5, sq = 2.0f * c5 * s5;      // d*2pi/2048
    float c4s = cq * cq - sq * sq, s4s = 2.0f * cq * sq;    // d*2pi/1024
    // stage 4 (q=256): same twiddle for all quads
    if (T == 0) {
        #pragma unroll
        for (int a = 0; a < 4; ++a)
            b4(xr[4*a], xi[4*a], xr[4*a+1], xi[4*a+1], xr[4*a+2], xi[4*a+2], xr[4*a+3], xi[4*a+3]);
    } else {
        #pragma unroll
        for (int a = 0; a < 4; ++a)
            b4t(xr[4*a], xi[4*a], xr[4*a+1], xi[4*a+1], xr[4*a+2], xi[4*a+2], xr[4*a+3], xi[4*a+3],
                c4s, s4s);
    }
    // stage 5 (q=1024): ang = base5 + m0*pi/8
    #pragma unroll
    for (int m0 = 0; m0 < 4; ++m0) {
        float c = c5 * C16[m0] - s5 * S16[m0];
        float s = s5 * C16[m0] + c5 * S16[m0];
        if (m0 == 0 && T == 0)
            b4(xr[0], xi[0], xr[4], xi[4], xr[8], xi[8], xr[12], xi[12]);
        else
            b4t(xr[m0], xi[m0], xr[m0+4], xi[m0+4], xr[m0+8], xi[m0+8], xr[m0+12], xi[m0+12], c, s);
    }

    // ---- window + overlap-add. w(n)/N = (1 - cos(2pi n/4096)) * 0.75/2^24.
    // cos(2pi n/4096) with n = 256m + d: rotate (c5,s5) by W16^m (free: reuse base5).
    const float K = 4.4703483581542969e-8f;      // 0.75 / 16777216
    const int base = (t << 10) - CROP;
    #pragma unroll
    for (int m = 0; m < 16; ++m) {
        float cn = c5 * C16[m] - s5 * S16[m];
        float wn = (1.0f - cn) * K;
        int P = base + (m << 8) + T;
        if (P >= 0 && P < LOUT) {
            atomicAdd(&out[P],        xr[m] * wn);
            atomicAdd(&out[LOUT + P], xi[m] * wn);
        }
    }
}

// ---------------- fallback FFT (R4 gather version, used only if ws too small) ----------------
__device__ __forceinline__ int drev12(int k) {
    unsigned r = __brev((unsigned)k) >> 20;
    r = ((r & 0x555u) << 1) | ((r >> 1) & 0x555u);
    return (int)r;
}
__device__ __forceinline__ int SWg(int p) { return p ^ ((p >> 5) & 31); }

__global__ __launch_bounds__(256) void fft_frames_gather(
    const float* __restrict__ zr, const float* __restrict__ zi,
    const float* __restrict__ window, float* __restrict__ out)
{
    __shared__ float sre[NFFT];
    __shared__ float sim[NFFT];
    const int t = blockIdx.x;
    const int tid = threadIdx.x;
    #pragma unroll
    for (int i = 0; i < NFFT / 256; ++i) {
        int p = tid + i * 256;
        int k = drev12(p);
        int f = (k <= NFFT / 2) ? k : (NFFT - k);
        float sg = (k <= NFFT / 2) ? 1.0f : -1.0f;
        float a = zr[f * TFRAMES + t];
        float b = zi[f * TFRAMES + t] * sg;
        int q = SWg(p);
        sre[q] = a;  sim[q] = b;
    }
    __syncthreads();
    #pragma unroll
    for (int s = 0; s < 6; ++s) {
        const int q = 1 << (2 * s);
        #pragma unroll
        for (int bb = 0; bb < 4; ++bb) {
            const int b = tid + bb * 256;
            const int jj = b & (q - 1);
            const int i0 = ((b >> (2 * s)) << (2 * s + 2)) + jj;
            const int p0 = SWg(i0), p1 = SWg(i0 + q), p2 = SWg(i0 + 2 * q), p3 = SWg(i0 + 3 * q);
            float ang = (float)jj * (6.283185307179586f / (float)(4 * q));
            float s1, c1; __sincosf(ang, &s1, &c1);
            float r0 = sre[p0], i0v = sim[p0], r1 = sre[p1], i1 = sim[p1];
            float r2 = sre[p2], i2 = sim[p2], r3 = sre[p3], i3 = sim[p3];
            b4t(r0, i0v, r1, i1, r2, i2, r3, i3, c1, s1);
            sre[p0] = r0; sim[p0] = i0v;  sre[p1] = r1; sim[p1] = i1;
            sre[p2] = r2; sim[p2] = i2;   sre[p3] = r3; sim[p3] = i3;
        }
        __syncthreads();
    }
    const int base = (t << 10) - CROP;
    #pragma unroll
    for (int i = 0; i < NFFT / 256; ++i) {
        int n = tid + i * 256;
        float w = window[n] * (1.0f / (float)NFFT);
        int p = SWg(n);
        int P = base + n;
        if (P >= 0 && P < LOUT) {
            atomicAdd(&out[P],        sre[p] * w);
            atomicAdd(&out[LOUT + P], sim[p] * w);
        }
    }
}

// ---------------- normalize: interior wsum == 3/4096 exactly ----------------
__global__ __launch_bounds__(256) void normalize_inplace(
    const float* __restrict__ window,
    float* __restrict__ out)
{
    int idx = blockIdx.x * 256 + threadIdx.x;
    int p = idx * 4;
    if (p >= LOUT) return;
    if (p >= 1024 && p < LOUT - 1024) {
        const float inv = (float)NFFT / 3.0f;
        float4* o0 = (float4*)(out + p);
        float4* o1 = (float4*)(out + LOUT + p);
        float4 a = *o0, b = *o1;
        a.x *= inv; a.y *= inv; a.z *= inv; a.w *= inv;
        b.x *= inv; b.y *= inv; b.z *= inv; b.w *= inv;
        *o0 = a; *o1 = b;
    } else {
        for (int e = 0; e < 4; ++e) {
            int pe = p + e;
            int P = pe + CROP;
            int t_hi = min(TFRAMES - 1, P >> 10);
            int t_lo = max(0, (P - (NFFT - HOP)) >> 10);
            float ws = 0.0f;
            for (int tt = t_lo; tt <= t_hi; ++tt) ws += window[P - (tt << 10)];
            float inv = (ws >= 1e-6f) ? (1.0f / ws) : 1.0f;
            out[pe]        *= inv;
            out[LOUT + pe] *= inv;
        }
    }
}

extern "C" void kernel_launch(void* const* d_in, const int* in_sizes, int n_in,
                              void* d_out, int out_size, void* d_ws, size_t ws_size,
                              hipStream_t stream) {
    const float* z      = (const float*)d_in[0];
    const float* window = (const float*)d_in[1];
    float* out = (float*)d_out;   // 2*LOUT floats; doubles as the OLA accumulator

    hipMemsetAsync(out, 0, (size_t)2 * LOUT * sizeof(float), stream);

    const size_t ws_needed = (size_t)2 * TFRAMES * RS * sizeof(float);  // 67.6 MB
    if (ws_size >= ws_needed) {
        float* zt = (float*)d_ws;
        transpose64<<<dim3(32, 64, 2), 256, 0, stream>>>(z, zt);
        edge2048<<<32, 256, 0, stream>>>(z, zt);
        fft_reg<<<TFRAMES, 256, 0, stream>>>(zt, out);
    } else {
        const float* zr = z;
        const float* zi = z + (size_t)NBINS * TFRAMES;
        fft_frames_gather<<<TFRAMES, 256, 0, stream>>>(zr, zi, window, out);
    }
    normalize_inplace<<<(LOUT / 4 + 255) / 256, 256, 0, stream>>>(window, out);
}

// Round 7
// 211.374 us; speedup vs baseline: 1.4024x; 1.1674x over previous
//
#include <hip/hip_runtime.h>

#define NFFT    4096
#define NBINS   2049
#define TFRAMES 4096
#define HOP     1024
#define LFULL   4197376   // (TFRAMES-1)*HOP + NFFT
#define LOUT    4193280   // LFULL - NFFT  (== out_size/2 exactly)
#define CROP    2048      // NFFT/2
#define RS      2064      // transposed row stride in floats (16B-aligned rows)
#define P0TAIL  4192256   // last even-group tile ends here (4096*1022-2048+8192)

// ---- per-phase LDS swizzles (all 4 access patterns 2-way max = free) ----
__device__ __forceinline__ int SW1(int p) {
    return p ^ (((p >> 6) & 3) | (((p >> 9) & 3) << 2) | (((p >> 8) & 1) << 4));
}
__device__ __forceinline__ int SW2(int p) {
    return p ^ (((p >> 8) & 3) << 3);
}

// radix-4 DIT butterfly, no twiddle
__device__ __forceinline__ void b4(float& x0r, float& x0i, float& x1r, float& x1i,
                                   float& x2r, float& x2i, float& x3r, float& x3i) {
    float a0r = x0r + x2r, a0i = x0i + x2i;
    float a1r = x0r - x2r, a1i = x0i - x2i;
    float a2r = x1r + x3r, a2i = x1i + x3i;
    float a3r = x1r - x3r, a3i = x1i - x3i;
    x0r = a0r + a2r;  x0i = a0i + a2i;
    x1r = a1r - a3i;  x1i = a1i + a3r;   // inverse FFT: y1 = a1 + i*a3
    x2r = a0r - a2r;  x2i = a0i - a2i;
    x3r = a1r + a3i;  x3i = a1i - a3r;
}

// radix-4 DIT butterfly with twiddle w = e^{+i*ang} = (c1,s1)
__device__ __forceinline__ void b4t(float& x0r, float& x0i, float& x1r, float& x1i,
                                    float& x2r, float& x2i, float& x3r, float& x3i,
                                    float c1, float s1) {
    float c2 = c1 * c1 - s1 * s1, s2 = 2.0f * c1 * s1;
    float c3 = c2 * c1 - s2 * s1, s3 = c2 * s1 + s2 * c1;
    float t1r = x1r * c1 - x1i * s1, t1i = x1r * s1 + x1i * c1;
    float t2r = x2r * c2 - x2i * s2, t2i = x2r * s2 + x2i * c2;
    float t3r = x3r * c3 - x3i * s3, t3i = x3r * s3 + x3i * c3;
    float a0r = x0r + t2r, a0i = x0i + t2i;
    float a1r = x0r - t2r, a1i = x0i - t2i;
    float a2r = t1r + t3r, a2i = t1i + t3i;
    float a3r = t1r - t3r, a3i = t1i - t3i;
    x0r = a0r + a2r;  x0i = a0i + a2i;
    x1r = a1r - a3i;  x1i = a1i + a3r;
    x2r = a0r - a2r;  x2i = a0i - a2i;
    x3r = a1r + a3i;  x3i = a1i - a3r;
}

#define C16_INIT { 1.0f,  0.923879532511287f,  0.707106781186548f,  0.382683432365090f, \
                   0.0f, -0.382683432365090f, -0.707106781186548f, -0.923879532511287f, \
                  -1.0f, -0.923879532511287f, -0.707106781186548f, -0.382683432365090f, \
                   0.0f,  0.382683432365090f,  0.707106781186548f,  0.923879532511287f }
#define S16_INIT { 0.0f,  0.382683432365090f,  0.707106781186548f,  0.923879532511287f, \
                   1.0f,  0.923879532511287f,  0.707106781186548f,  0.382683432365090f, \
                   0.0f, -0.382683432365090f, -0.707106781186548f, -0.923879532511287f, \
                  -1.0f, -0.923879532511287f, -0.707106781186548f, -0.382683432365090f }

// ---------------- transpose: z[ch][f][t] -> zt[ch][t][f], 64x64 float4 tiles ----------------
__global__ __launch_bounds__(256) void transpose64(
    const float* __restrict__ z, float* __restrict__ zt)
{
    __shared__ float tile[64][65];
    const int ch = blockIdx.z;
    const int f0 = blockIdx.x * 64;
    const int t0 = blockIdx.y * 64;
    const int tx = threadIdx.x & 15;
    const int ty = threadIdx.x >> 4;
    const float* src = z + (size_t)ch * NBINS * TFRAMES;
    float* dst = zt + (size_t)ch * TFRAMES * RS;

    #pragma unroll
    for (int k = 0; k < 4; ++k) {
        int fl = ty + 16 * k;
        float4 v = *(const float4*)(src + (size_t)(f0 + fl) * TFRAMES + t0 + 4 * tx);
        tile[fl][4 * tx + 0] = v.x;
        tile[fl][4 * tx + 1] = v.y;
        tile[fl][4 * tx + 2] = v.z;
        tile[fl][4 * tx + 3] = v.w;
    }
    __syncthreads();
    #pragma unroll
    for (int k = 0; k < 4; ++k) {
        int tl = ty + 16 * k;
        float4 v = make_float4(tile[4 * tx + 0][tl], tile[4 * tx + 1][tl],
                               tile[4 * tx + 2][tl], tile[4 * tx + 3][tl]);
        *(float4*)(dst + (size_t)(t0 + tl) * RS + f0 + 4 * tx) = v;
    }
}

__global__ __launch_bounds__(256) void edge2048(
    const float* __restrict__ z, float* __restrict__ zt)
{
    int i = blockIdx.x * 256 + threadIdx.x;      // 0 .. 8191
    int ch = i >> 12, t = i & 4095;
    zt[(size_t)ch * TFRAMES * RS + (size_t)t * RS + 2048] =
        z[(size_t)ch * NBINS * TFRAMES + (size_t)2048 * TFRAMES + t];
}

// ---------------- 4 frames/block: register IFFT + register OLA + plain plane stores ----------------
// Tile map: frame t=4g+k, sample n=256m+T -> cropped Q = 4096g - 2048 + 256*(4k+m) + T.
// Group tile = 32 chunks (8192 samples) at Sc = 4096g - 2048; slots 0..27 hold data,
// 28..31 zero-pad. Same-parity groups tile disjointly (stride 8192) -> 2 planes, no atomics.
__global__ __launch_bounds__(256) void fft4(
    const float* __restrict__ zt,      // [2][TFRAMES][RS]
    float* __restrict__ planes)        // [2 planes][2 ch][LOUT]
{
    __shared__ float LRe[NFFT];
    __shared__ float LIm[NFFT];
    const int g = blockIdx.x;          // frame group: frames 4g..4g+3
    const int T = threadIdx.x;
    const float C16[16] = C16_INIT;
    const float S16[16] = S16_INIT;

    // ---- twiddles: depend only on T -> hoisted out of the frame loop
    const int H = T >> 4, j = T & 15;
    float cb, sb;
    __sincosf((float)j * (6.283185307179586f / 256.0f), &sb, &cb);
    float cd = cb * cb - sb * sb, sd = 2.0f * cb * sb;
    float c2s = cd * cd - sd * sd, s2s = 2.0f * cd * sd;    // j*2pi/64
    float c5, s5;
    __sincosf((float)T * (6.283185307179586f / 4096.0f), &s5, &c5);
    float cq = c5 * c5 - s5 * s5, sq = 2.0f * c5 * s5;
    float c4s = cq * cq - sq * sq, s4s = 2.0f * cq * sq;    // T*2pi/1024

    const float K = 4.4703483581542969e-8f;  // 0.5 * (1.5/NFFT) / NFFT
    float accr[28], acci[28];
    #pragma unroll
    for (int i = 0; i < 28; ++i) { accr[i] = 0.0f; acci[i] = 0.0f; }

    #pragma unroll
    for (int k = 0; k < 4; ++k) {
        const int t = 4 * g + k;
        const float* rowr = zt + (size_t)t * RS;
        const float* rowi = zt + (size_t)TFRAMES * RS + (size_t)t * RS;
        float xr[16], xi[16];

        // Phase A: n = 256m + T (coalesced), Hermitian mirror for n > 2048
        #pragma unroll
        for (int m = 0; m < 16; ++m) {
            int r = ((m & 3) << 2) | (m >> 2);       // drev4
            int n = (m << 8) + T;
            if (n <= 2048) { xr[r] = rowr[n]; xi[r] = rowi[n]; }
            else { int f = NFFT - n; xr[r] = rowr[f]; xi[r] = -rowi[f]; }
        }
        #pragma unroll
        for (int a = 0; a < 4; ++a)
            b4(xr[4*a], xi[4*a], xr[4*a+1], xi[4*a+1], xr[4*a+2], xi[4*a+2], xr[4*a+3], xi[4*a+3]);
        b4(xr[0], xi[0], xr[4], xi[4], xr[8], xi[8], xr[12], xi[12]);
        #pragma unroll
        for (int r0 = 1; r0 < 4; ++r0)
            b4t(xr[r0], xi[r0], xr[r0+4], xi[r0+4], xr[r0+8], xi[r0+8], xr[r0+12], xi[r0+12],
                C16[r0], S16[r0]);
        {
            int G = ((T & 3) << 6) | (((T >> 2) & 3) << 4) | (((T >> 4) & 3) << 2) | ((T >> 6) & 3);
            int p0 = G << 4;
            #pragma unroll
            for (int r = 0; r < 16; ++r) {
                int a = SW1(p0 + r);
                LRe[a] = xr[r];  LIm[a] = xi[r];
            }
        }
        __syncthreads();

        // Phase B
        #pragma unroll
        for (int s = 0; s < 16; ++s) {
            int a = SW1((H << 8) + (s << 4) + j);
            xr[s] = LRe[a];  xi[s] = LIm[a];
        }
        if (j == 0) {
            #pragma unroll
            for (int a = 0; a < 4; ++a)
                b4(xr[4*a], xi[4*a], xr[4*a+1], xi[4*a+1], xr[4*a+2], xi[4*a+2], xr[4*a+3], xi[4*a+3]);
        } else {
            #pragma unroll
            for (int a = 0; a < 4; ++a)
                b4t(xr[4*a], xi[4*a], xr[4*a+1], xi[4*a+1], xr[4*a+2], xi[4*a+2], xr[4*a+3], xi[4*a+3],
                    c2s, s2s);
        }
        #pragma unroll
        for (int s0 = 0; s0 < 4; ++s0) {
            float c = cb * C16[s0] - sb * S16[s0];
            float s = sb * C16[s0] + cb * S16[s0];
            if (s0 == 0 && j == 0)
                b4(xr[0], xi[0], xr[4], xi[4], xr[8], xi[8], xr[12], xi[12]);
            else
                b4t(xr[s0], xi[s0], xr[s0+4], xi[s0+4], xr[s0+8], xi[s0+8], xr[s0+12], xi[s0+12], c, s);
        }
        __syncthreads();
        #pragma unroll
        for (int s = 0; s < 16; ++s) {
            int a = SW2((H << 8) + (s << 4) + j);
            LRe[a] = xr[s];  LIm[a] = xi[s];
        }
        __syncthreads();

        // Phase C: output n = 256m + T
        #pragma unroll
        for (int m = 0; m < 16; ++m) {
            int a = SW2((m << 8) + T);
            xr[m] = LRe[a];  xi[m] = LIm[a];
        }
        __syncthreads();   // LDS reads done; next frame may overwrite
        if (T == 0) {
            #pragma unroll
            for (int a = 0; a < 4; ++a)
                b4(xr[4*a], xi[4*a], xr[4*a+1], xi[4*a+1], xr[4*a+2], xi[4*a+2], xr[4*a+3], xi[4*a+3]);
        } else {
            #pragma unroll
            for (int a = 0; a < 4; ++a)
                b4t(xr[4*a], xi[4*a], xr[4*a+1], xi[4*a+1], xr[4*a+2], xi[4*a+2], xr[4*a+3], xi[4*a+3],
                    c4s, s4s);
        }
        #pragma unroll
        for (int m0 = 0; m0 < 4; ++m0) {
            float c = c5 * C16[m0] - s5 * S16[m0];
            float s = s5 * C16[m0] + c5 * S16[m0];
            if (m0 == 0 && T == 0)
                b4(xr[0], xi[0], xr[4], xi[4], xr[8], xi[8], xr[12], xi[12]);
            else
                b4t(xr[m0], xi[m0], xr[m0+4], xi[m0+4], xr[m0+8], xi[m0+8], xr[m0+12], xi[m0+12], c, s);
        }

        // window + register OLA: frame k's chunk m lands at acc slot m + 4k
        #pragma unroll
        for (int m = 0; m < 16; ++m) {
            float cn = c5 * C16[m] - s5 * S16[m];      // cos(2pi*n/4096), n = 256m+T
            float wn = (1.0f - cn) * K;
            accr[m + 4 * k] += xr[m] * wn;
            acci[m + 4 * k] += xi[m] * wn;
        }
    }

    // ---- plain coalesced stores to parity plane; zero-pad chunks 28..31 tile the plane
    const int plane = g & 1;
    float* pr = planes + (size_t)plane * 2 * LOUT;
    float* pim = pr + LOUT;
    const int Sc = (g << 12) - 2048;                   // cropped tile start (FIXED: was -4096)
    #pragma unroll
    for (int mp = 0; mp < 32; ++mp) {
        int Q = Sc + (mp << 8) + T;
        if ((unsigned)Q < (unsigned)LOUT) {
            pr[Q]  = (mp < 28) ? accr[mp] : 0.0f;
            pim[Q] = (mp < 28) ? acci[mp] : 0.0f;
        }
    }
}

// ---------------- sum 2 planes + normalize -> out ----------------
__global__ __launch_bounds__(256) void normalize_planes(
    const float* __restrict__ planes,
    const float* __restrict__ window,
    float* __restrict__ out)
{
    int idx = blockIdx.x * 256 + threadIdx.x;
    int p = idx * 4;
    if (p >= LOUT) return;
    const float* p0r = planes;
    const float* p0i = planes + LOUT;
    const float* p1r = planes + 2 * (size_t)LOUT;
    const float* p1i = planes + 3 * (size_t)LOUT;
    float4 a0 = *(const float4*)(p0r + p), a1 = *(const float4*)(p1r + p);
    float4 b0 = *(const float4*)(p0i + p), b1 = *(const float4*)(p1i + p);
    float4 a = make_float4(a0.x + a1.x, a0.y + a1.y, a0.z + a1.z, a0.w + a1.w);
    float4 b = make_float4(b0.x + b1.x, b0.y + b1.y, b0.z + b1.z, b0.w + b1.w);
    if (p >= 1024 && p < LOUT - 1024) {
        const float inv = (float)NFFT / 3.0f;          // interior wsum = 3/4096 exactly
        a.x *= inv; a.y *= inv; a.z *= inv; a.w *= inv;
        b.x *= inv; b.y *= inv; b.z *= inv; b.w *= inv;
        *(float4*)(out + p) = a;
        *(float4*)(out + LOUT + p) = b;
    } else {
        float ar[4] = {a.x, a.y, a.z, a.w};
        float br[4] = {b.x, b.y, b.z, b.w};
        for (int e = 0; e < 4; ++e) {
            int P = p + e + CROP;
            int t_hi = min(TFRAMES - 1, P >> 10);
            int t_lo = max(0, (P - (NFFT - HOP)) >> 10);
            float ws = 0.0f;
            for (int tt = t_lo; tt <= t_hi; ++tt) ws += window[P - (tt << 10)];
            float inv = (ws >= 1e-6f) ? (1.0f / ws) : 1.0f;
            out[p + e]        = ar[e] * inv;
            out[LOUT + p + e] = br[e] * inv;
        }
    }
}

// ================= fallback path (ws too small for planes): R5 atomic version =================
__global__ __launch_bounds__(256) void fft_reg(
    const float* __restrict__ zt, float* __restrict__ out)
{
    __shared__ float LRe[NFFT];
    __shared__ float LIm[NFFT];
    const int t = blockIdx.x;
    const int T = threadIdx.x;
    const float C16[16] = C16_INIT;
    const float S16[16] = S16_INIT;
    const float* rowr = zt + (size_t)t * RS;
    const float* rowi = zt + (size_t)TFRAMES * RS + (size_t)t * RS;
    float xr[16], xi[16];
    #pragma unroll
    for (int m = 0; m < 16; ++m) {
        int r = ((m & 3) << 2) | (m >> 2);
        int n = (m << 8) + T;
        if (n <= 2048) { xr[r] = rowr[n]; xi[r] = rowi[n]; }
        else { int f = NFFT - n; xr[r] = rowr[f]; xi[r] = -rowi[f]; }
    }
    #pragma unroll
    for (int a = 0; a < 4; ++a)
        b4(xr[4*a], xi[4*a], xr[4*a+1], xi[4*a+1], xr[4*a+2], xi[4*a+2], xr[4*a+3], xi[4*a+3]);
    b4(xr[0], xi[0], xr[4], xi[4], xr[8], xi[8], xr[12], xi[12]);
    #pragma unroll
    for (int r0 = 1; r0 < 4; ++r0)
        b4t(xr[r0], xi[r0], xr[r0+4], xi[r0+4], xr[r0+8], xi[r0+8], xr[r0+12], xi[r0+12],
            C16[r0], S16[r0]);
    {
        int G = ((T & 3) << 6) | (((T >> 2) & 3) << 4) | (((T >> 4) & 3) << 2) | ((T >> 6) & 3);
        int p0 = G << 4;
        #pragma unroll
        for (int r = 0; r < 16; ++r) { int a = SW1(p0 + r); LRe[a] = xr[r]; LIm[a] = xi[r]; }
    }
    __syncthreads();
    const int H = T >> 4, j = T & 15;
    #pragma unroll
    for (int s = 0; s < 16; ++s) { int a = SW1((H << 8) + (s << 4) + j); xr[s] = LRe[a]; xi[s] = LIm[a]; }
    float cb, sb;
    __sincosf((float)j * (6.283185307179586f / 256.0f), &sb, &cb);
    float cd = cb * cb - sb * sb, sd = 2.0f * cb * sb;
    float c2s = cd * cd - sd * sd, s2s = 2.0f * cd * sd;
    if (j == 0) {
        #pragma unroll
        for (int a = 0; a < 4; ++a)
            b4(xr[4*a], xi[4*a], xr[4*a+1], xi[4*a+1], xr[4*a+2], xi[4*a+2], xr[4*a+3], xi[4*a+3]);
    } else {
        #pragma unroll
        for (int a = 0; a < 4; ++a)
            b4t(xr[4*a], xi[4*a], xr[4*a+1], xi[4*a+1], xr[4*a+2], xi[4*a+2], xr[4*a+3], xi[4*a+3],
                c2s, s2s);
    }
    #pragma unroll
    for (int s0 = 0; s0 < 4; ++s0) {
        float c = cb * C16[s0] - sb * S16[s0];
        float s = sb * C16[s0] + cb * S16[s0];
        if (s0 == 0 && j == 0) b4(xr[0], xi[0], xr[4], xi[4], xr[8], xi[8], xr[12], xi[12]);
        else b4t(xr[s0], xi[s0], xr[s0+4], xi[s0+4], xr[s0+8], xi[s0+8], xr[s0+12], xi[s0+12], c, s);
    }
    __syncthreads();
    #pragma unroll
    for (int s = 0; s < 16; ++s) { int a = SW2((H << 8) + (s << 4) + j); LRe[a] = xr[s]; LIm[a] = xi[s]; }
    __syncthreads();
    #pragma unroll
    for (int m = 0; m < 16; ++m) { int a = SW2((m << 8) + T); xr[m] = LRe[a]; xi[m] = LIm[a]; }
    float c5, s5;
    __sincosf((float)T * (6.283185307179586f / 4096.0f), &s5, &c5);
    float cq = c5 * c5 - s5 * s5, sq = 2.0f * c5 * s5;
    float c4s = cq * cq - sq * sq, s4s = 2.0f * cq * sq;
    if (T == 0) {
        #pragma unroll
        for (int a = 0; a < 4; ++a)
            b4(xr[4*a], xi[4*a], xr[4*a+1], xi[4*a+1], xr[4*a+2], xi[4*a+2], xr[4*a+3], xi[4*a+3]);
    } else {
        #pragma unroll
        for (int a = 0; a < 4; ++a)
            b4t(xr[4*a], xi[4*a], xr[4*a+1], xi[4*a+1], xr[4*a+2], xi[4*a+2], xr[4*a+3], xi[4*a+3],
                c4s, s4s);
    }
    #pragma unroll
    for (int m0 = 0; m0 < 4; ++m0) {
        float c = c5 * C16[m0] - s5 * S16[m0];
        float s = s5 * C16[m0] + c5 * S16[m0];
        if (m0 == 0 && T == 0) b4(xr[0], xi[0], xr[4], xi[4], xr[8], xi[8], xr[12], xi[12]);
        else b4t(xr[m0], xi[m0], xr[m0+4], xi[m0+4], xr[m0+8], xi[m0+8], xr[m0+12], xi[m0+12], c, s);
    }
    const float K = 4.4703483581542969e-8f;
    const int base = (t << 10) - CROP;
    #pragma unroll
    for (int m = 0; m < 16; ++m) {
        float cn = c5 * C16[m] - s5 * S16[m];
        float wn = (1.0f - cn) * K;
        int P = base + (m << 8) + T;
        if (P >= 0 && P < LOUT) {
            atomicAdd(&out[P],        xr[m] * wn);
            atomicAdd(&out[LOUT + P], xi[m] * wn);
        }
    }
}

__global__ __launch_bounds__(256) void normalize_inplace(
    const float* __restrict__ window, float* __restrict__ out)
{
    int idx = blockIdx.x * 256 + threadIdx.x;
    int p = idx * 4;
    if (p >= LOUT) return;
    if (p >= 1024 && p < LOUT - 1024) {
        const float inv = (float)NFFT / 3.0f;
        float4* o0 = (float4*)(out + p);
        float4* o1 = (float4*)(out + LOUT + p);
        float4 a = *o0, b = *o1;
        a.x *= inv; a.y *= inv; a.z *= inv; a.w *= inv;
        b.x *= inv; b.y *= inv; b.z *= inv; b.w *= inv;
        *o0 = a; *o1 = b;
    } else {
        for (int e = 0; e < 4; ++e) {
            int pe = p + e;
            int P = pe + CROP;
            int t_hi = min(TFRAMES - 1, P >> 10);
            int t_lo = max(0, (P - (NFFT - HOP)) >> 10);
            float ws = 0.0f;
            for (int tt = t_lo; tt <= t_hi; ++tt) ws += window[P - (tt << 10)];
            float inv = (ws >= 1e-6f) ? (1.0f / ws) : 1.0f;
            out[pe]        *= inv;
            out[LOUT + pe] *= inv;
        }
    }
}

extern "C" void kernel_launch(void* const* d_in, const int* in_sizes, int n_in,
                              void* d_out, int out_size, void* d_ws, size_t ws_size,
                              hipStream_t stream) {
    const float* z      = (const float*)d_in[0];
    const float* window = (const float*)d_in[1];
    float* out = (float*)d_out;

    const size_t zt_floats = (size_t)2 * TFRAMES * RS;            // 16,908,288
    const size_t ws_need_B = zt_floats * sizeof(float);           // 67.6 MB (atomic path)
    const size_t ws_need_A = (zt_floats + (size_t)4 * LOUT) * sizeof(float);  // 134.7 MB

    if (ws_size >= ws_need_A) {
        float* zt     = (float*)d_ws;
        float* planes = zt + zt_floats;
        transpose64<<<dim3(32, 64, 2), 256, 0, stream>>>(z, zt);
        edge2048<<<32, 256, 0, stream>>>(z, zt);
        // plane-0 tail gap [P0TAIL, LOUT): no even tile covers it -> zero (4 KB x2)
        hipMemsetAsync(planes + P0TAIL, 0, (size_t)(LOUT - P0TAIL) * sizeof(float), stream);
        hipMemsetAsync(planes + (size_t)LOUT + P0TAIL, 0, (size_t)(LOUT - P0TAIL) * sizeof(float), stream);
        // plane-1 head gap [0, 2048): no odd tile covers it -> zero (8 KB x2)
        hipMemsetAsync(planes + (size_t)2 * LOUT, 0, (size_t)2048 * sizeof(float), stream);
        hipMemsetAsync(planes + (size_t)3 * LOUT, 0, (size_t)2048 * sizeof(float), stream);
        fft4<<<TFRAMES / 4, 256, 0, stream>>>(zt, planes);
        normalize_planes<<<(LOUT / 4 + 255) / 256, 256, 0, stream>>>(planes, window, out);
    } else if (ws_size >= ws_need_B) {
        float* zt = (float*)d_ws;
        hipMemsetAsync(out, 0, (size_t)2 * LOUT * sizeof(float), stream);
        transpose64<<<dim3(32, 64, 2), 256, 0, stream>>>(z, zt);
        edge2048<<<32, 256, 0, stream>>>(z, zt);
        fft_reg<<<TFRAMES, 256, 0, stream>>>(zt, out);
        normalize_inplace<<<(LOUT / 4 + 255) / 256, 256, 0, stream>>>(window, out);
    }
}